// Round 18
// baseline (271.910 us; speedup 1.0000x reference)
//
#include <hip/hip_runtime.h>
#include <hip/hip_bf16.h>

#define EPSV 1e-5f

// workspace layout: [wB2][xTp][stats]
#define WB2_ELEMS (2*8*36*128*32)          // [p][nt(8)][kt(36)][nl(128)][kk(32)] bf16
#define WB2_BYTES ((size_t)WB2_ELEMS*2)    // 4,718,592
#define XTP_ELEMS (8*68*68*128)            // padded channels-last x, bf16
#define XTP_BYTES ((size_t)XTP_ELEMS*2)    // 9,469,952
#define STATS_OFF (WB2_BYTES + XTP_BYTES)  // 1024 float2 partials

typedef __attribute__((ext_vector_type(8))) short short8;
typedef __attribute__((ext_vector_type(4))) float f32x4;

// ---------------------------------------------------------------------------
// x [8][128][64][64] f32  ->  xTp [8][68][68][128] bf16 (2-px zero halo)
__global__ __launch_bounds__(256) void k_xpad(const float* __restrict__ x,
                                              __hip_bfloat16* __restrict__ xTp) {
    int bh = blockIdx.x; int b = bh >> 6, h = bh & 63;
    __shared__ __hip_bfloat16 tile[64][130];
    int t = threadIdx.x;
#pragma unroll
    for (int i = 0; i < 32; ++i) {
        int e = (i << 8) + t; int w = e & 63; int ci = e >> 6;
        tile[w][ci] = __float2bfloat16(x[(((size_t)(b*128 + ci))*64 + h)*64 + w]);
    }
    __syncthreads();
    __hip_bfloat16* dst = xTp + ((size_t)((b*68 + h + 2)*68 + 2))*128;
#pragma unroll
    for (int i = 0; i < 32; ++i) {
        int e = (i << 8) + t; int ci = e & 127; int w = e >> 7;
        dst[w*128 + ci] = tile[w][ci];
    }
}

// ---------------------------------------------------------------------------
// w_mid [128][16][128][3][3] f32 -> wB2 [p][nt(8)][kt(36)][nl(128)][kk(32)]
__global__ void k_wrepack(const float* __restrict__ w_mid,
                          __hip_bfloat16* __restrict__ wB2) {
    int idx = blockIdx.x * 256 + threadIdx.x;
    if (idx >= WB2_ELEMS) return;
    int kk  = idx & 31;
    int nl  = (idx >> 5) & 127;
    int q   = idx >> 12;             // (p*8+nt)*36 + kt
    int kt  = q % 36;
    int pnt = q / 36;
    int nt  = pnt & 7, p = pnt >> 3;
    int c = ((nt*8 + (nl >> 4)) << 1) + p;
    int m = nl & 15;
    int k = kt*32 + kk;
    int tap = k >> 7, ci = k & 127;
    wB2[idx] = __float2bfloat16(w_mid[((size_t)((c*16 + m)*128 + ci))*9 + tap]);
}

// ---------------------------------------------------------------------------
// Persistent-A implicit-GEMM conv, barrier-free K-loop, FULLY PIPELINED:
// step u's MFMAs consume A-fragments ds_read at step u-1 (af[2] reg dbuf,
// straight-line unroll — R16-proven rotation) and B-fragments global-loaded
// at step u-2 (breg[3]). No exposed lgkm/vmcnt in steady state; no barriers.
// Co-resident blocks share nt (i_>>8 decode) so the 8 KB/step B slab is
// L1-resident after the first wave touches it.
__global__ __launch_bounds__(256, 2) void k_conv(
    const __hip_bfloat16* __restrict__ xTp,
    const __hip_bfloat16* __restrict__ wB2,
    const float* __restrict__ w_pt,
    const float* __restrict__ b_pt,
    float* __restrict__ y) {
    __shared__ __hip_bfloat16 Atile[4*240*32];   // 61,440 B; plane kc: ci kc*32..+32

    const int combo = blockIdx.x & 7;      // XCD
    const int p   = combo & 1;
    const int ntp = combo >> 1;            // nt-pair 0..3
    const int i_  = blockIdx.x >> 3;       // 0..511
    const int nt  = ntp*2 + (i_ >> 8);     // consecutive blocks share nt (L1 reuse)
    const int mt  = i_ & 255;              // 0..255
    const int dil = 1 + p;
    const int b  = mt >> 5;                // image
    const int hb = (mt >> 2) & 7;          // row-block: output rows hb*8..+8
    const int wb = mt & 3;                 // col-block: output cols wb*16..+16
    const int H0 = hb*8, W0 = wb*16;       // halo origin (padded coords)

    const int t = threadIdx.x, lane = t & 63, wave = t >> 6;
    const int wm = wave >> 1, wn = wave & 1;
    const int lm = lane & 15, lg = lane >> 4;

    // ---- stage halo once: 4 planes x 240 px x 4 slots = 3840 units, 15 passes
    // phys slot = ls ^ ((px>>1)&3)   (R6 mechanism, R10/R17 zero-conflict shape)
    {
        const size_t gbase = ((size_t)(b*68 + H0))*68 + W0;
#pragma unroll
        for (int pass = 0; pass < 15; ++pass) {
            int si  = pass*256 + t;          // 0..3839
            int kc  = si / 960;
            int rem = si - kc*960;
            int px  = rem >> 2;
            int ls  = rem & 3;
            int prow = px / 20, pcol = px - prow*20;
            short8 v = *(const short8*)(xTp + (gbase + prow*68 + pcol)*128
                                        + kc*32 + ls*8);
            int phys = ls ^ ((px >> 1) & 3);
            *(short8*)(Atile + (kc*960 + px*4 + phys)*8) = v;
        }
    }

    // B pointer (R7/R17-proven): frag j at step u = +u*4096 + j*512
    const __hip_bfloat16* bptr = wB2 + (size_t)p*(8*36*4096) + (size_t)nt*(36*4096)
                               + (wn*64 + lm)*32 + lg*8;

    f32x4 acc[4][4];
#pragma unroll
    for (int i = 0; i < 4; ++i)
#pragma unroll
        for (int j = 0; j < 4; ++j) acc[i][j] = (f32x4){0.f, 0.f, 0.f, 0.f};

    // B prologue: steps 0,1 into breg[0],breg[1]
    short8 breg[3][4];
#pragma unroll
    for (int j = 0; j < 4; ++j) breg[0][j] = *(const short8*)(bptr + j*512);
#pragma unroll
    for (int j = 0; j < 4; ++j) breg[1][j] = *(const short8*)(bptr + 4096 + j*512);

    __syncthreads();   // staging visible; the ONLY block-wide barrier

    // A fragment read into a named dbuf slot (compile-time tap)
#define LOADA(dst, khc, kwc, kcc) do {                                        \
    int pc_ = 2 + dil*(kwc) + lm;                                             \
    int pr_ = (wm*4 + 2 + dil*(khc))*20 + pc_;                                \
    _Pragma("unroll")                                                         \
    for (int i_a = 0; i_a < 4; ++i_a) {                                       \
        int px_ = pr_ + 20*i_a;                                               \
        dst[i_a] = *(const short8*)(Atile + (kcc)*7680 + px_*32               \
                                    + ((lg ^ ((px_ >> 1) & 3)) << 3));        \
    }                                                                         \
  } while (0)

    short8 af[2][4];
    LOADA(af[0], -1, -1, 0);   // fragments for step u=0 (tap 0, kc 0)

#pragma unroll
    for (int u = 0; u < 36; ++u) {
        // B prefetch for step u+2 (distance-2, static %3 rotation)
        if (u + 2 < 36) {
#pragma unroll
            for (int j = 0; j < 4; ++j)
                breg[(u+2)%3][j] = *(const short8*)(bptr + (size_t)(u+2)*4096 + j*512);
        }
        // A fragment prefetch for step u+1 (lgkm hidden under this step's MFMAs)
        if (u + 1 < 36) {
            const int un = u + 1, tapn = un >> 2, kcn = un & 3;
            const int khn = tapn/3 - 1, kwn = tapn%3 - 1;
            LOADA(af[(u+1)&1], khn, kwn, kcn);
        }
        __builtin_amdgcn_s_setprio(1);
#pragma unroll
        for (int i = 0; i < 4; ++i)
#pragma unroll
            for (int j = 0; j < 4; ++j)
                acc[i][j] = __builtin_amdgcn_mfma_f32_16x16x32_bf16(
                    af[u&1][i], breg[u%3][j], acc[i][j], 0, 0, 0);
        __builtin_amdgcn_s_setprio(0);
    }
#undef LOADA

    // epilogue: leaky -> *w_pt -> reduce over m (16 lanes) -> +b_pt -> y
#pragma unroll
    for (int j = 0; j < 4; ++j) {
        int n_g = nt*128 + wn*64 + j*16 + lm;
        int c = ((n_g >> 4) << 1) + p;     // uniform across the 16-lane group
        float wp = w_pt[c*16 + lm];        // m == lm
        float bp = b_pt[c];
#pragma unroll
        for (int i = 0; i < 4; ++i) {
            int h = H0 + wm*4 + i;
#pragma unroll
            for (int r = 0; r < 4; ++r) {
                float v = acc[i][j][r];
                v = v >= 0.f ? v : 0.1f*v;
                v *= wp;
                v += __shfl_xor(v, 1);
                v += __shfl_xor(v, 2);
                v += __shfl_xor(v, 4);
                v += __shfl_xor(v, 8);
                if (lm == 0) {
                    int w = W0 + lg*4 + r;
                    y[(size_t)(b*128 + c)*4096 + h*64 + w] = v + bp;
                }
            }
        }
    }
}

// ---------------------------------------------------------------------------
// per-(b,c)-plane partial sums (float4 loads, no atomics, deterministic)
__global__ __launch_bounds__(256) void k_ystat(const float* __restrict__ y,
                                               float2* __restrict__ partials) {
    int P = blockIdx.x;                 // plane = b*128 + c
    const float4* base = (const float4*)(y + (size_t)P*4096);
    int t = threadIdx.x;
    float s = 0.f, s2 = 0.f;
#pragma unroll
    for (int i = 0; i < 4; ++i) {
        float4 v = base[t + i*256];
        s  += v.x + v.y + v.z + v.w;
        s2 += v.x*v.x + v.y*v.y + v.z*v.z + v.w*v.w;
    }
#pragma unroll
    for (int o = 32; o; o >>= 1) { s += __shfl_down(s, o); s2 += __shfl_down(s2, o); }
    __shared__ float ss[4], ss2[4];
    if ((t & 63) == 0) { ss[t >> 6] = s; ss2[t >> 6] = s2; }
    __syncthreads();
    if (t == 0)
        partials[P] = make_float2(ss[0]+ss[1]+ss[2]+ss[3], ss2[0]+ss2[1]+ss2[2]+ss2[3]);
}

// BN finalize + apply + ReLU. Block covers 256 float4 = quarter of one plane.
__global__ __launch_bounds__(256) void k_bn_apply(float* __restrict__ y,
                                                  const float2* __restrict__ partials,
                                                  const float* __restrict__ gamma,
                                                  const float* __restrict__ beta) {
    int bid = blockIdx.x;
    int c = (bid >> 2) & 127;
    float s = 0.f, s2 = 0.f;
#pragma unroll
    for (int b = 0; b < 8; ++b) {
        float2 pr = partials[b*128 + c];
        s += pr.x; s2 += pr.y;
    }
    float mean = s * (1.f/32768.f);
    float var  = s2 * (1.f/32768.f) - mean*mean;
    float scale = gamma[c] * rsqrtf(var + EPSV);
    float shift = beta[c] - mean*scale;
    float4* y4 = (float4*)y;
    int idx = bid*256 + threadIdx.x;
    float4 v = y4[idx];
    v.x = fmaxf(v.x*scale + shift, 0.f);
    v.y = fmaxf(v.y*scale + shift, 0.f);
    v.z = fmaxf(v.z*scale + shift, 0.f);
    v.w = fmaxf(v.w*scale + shift, 0.f);
    y4[idx] = v;
}

// ---------------------------------------------------------------------------
extern "C" void kernel_launch(void* const* d_in, const int* in_sizes, int n_in,
                              void* d_out, int out_size, void* d_ws, size_t ws_size,
                              hipStream_t stream) {
    const float* x     = (const float*)d_in[0];
    const float* w_mid = (const float*)d_in[1];
    const float* w_pt  = (const float*)d_in[2];
    const float* b_pt  = (const float*)d_in[3];
    const float* gamma = (const float*)d_in[4];
    const float* beta  = (const float*)d_in[5];
    float* y = (float*)d_out;

    __hip_bfloat16* wB2 = (__hip_bfloat16*)d_ws;
    __hip_bfloat16* xTp = (__hip_bfloat16*)((char*)d_ws + WB2_BYTES);
    float2* partials    = (float2*)((char*)d_ws + STATS_OFF);

    hipMemsetAsync(xTp, 0, XTP_BYTES, stream);                  // zero halo
    k_xpad<<<512, 256, 0, stream>>>(x, xTp);
    k_wrepack<<<(WB2_ELEMS + 255) / 256, 256, 0, stream>>>(w_mid, wB2);
    k_conv<<<4096, 256, 0, stream>>>(xTp, wB2, w_pt, b_pt, y);
    k_ystat<<<1024, 256, 0, stream>>>(y, partials);
    k_bn_apply<<<4096, 256, 0, stream>>>(y, partials, gamma, beta);
}

// Round 19
// 267.200 us; speedup vs baseline: 1.0176x; 1.0176x over previous
//
#include <hip/hip_runtime.h>
#include <hip/hip_bf16.h>

#define EPSV 1e-5f

// workspace layout: [wB2][xTp][stats]
#define WB2_ELEMS (2*8*36*128*32)          // [p][nt(8)][kt(36)][nl(128)][kk(32)] bf16
#define WB2_BYTES ((size_t)WB2_ELEMS*2)    // 4,718,592
#define XTP_ELEMS (8*68*68*128)            // padded channels-last x, bf16
#define XTP_BYTES ((size_t)XTP_ELEMS*2)    // 9,469,952
#define STATS_OFF (WB2_BYTES + XTP_BYTES)  // 1024 float2 partials

typedef __attribute__((ext_vector_type(8))) short short8;
typedef __attribute__((ext_vector_type(4))) float f32x4;

// ---------------------------------------------------------------------------
// x [8][128][64][64] f32  ->  xTp [8][68][68][128] bf16 (2-px zero halo)
__global__ __launch_bounds__(256) void k_xpad(const float* __restrict__ x,
                                              __hip_bfloat16* __restrict__ xTp) {
    int bh = blockIdx.x; int b = bh >> 6, h = bh & 63;
    __shared__ __hip_bfloat16 tile[64][130];
    int t = threadIdx.x;
#pragma unroll
    for (int i = 0; i < 32; ++i) {
        int e = (i << 8) + t; int w = e & 63; int ci = e >> 6;
        tile[w][ci] = __float2bfloat16(x[(((size_t)(b*128 + ci))*64 + h)*64 + w]);
    }
    __syncthreads();
    __hip_bfloat16* dst = xTp + ((size_t)((b*68 + h + 2)*68 + 2))*128;
#pragma unroll
    for (int i = 0; i < 32; ++i) {
        int e = (i << 8) + t; int ci = e & 127; int w = e >> 7;
        dst[w*128 + ci] = tile[w][ci];
    }
}

// ---------------------------------------------------------------------------
// w_mid [128][16][128][3][3] f32 -> wB2 [p][nt(8)][kt(36)][nl(128)][kk(32)]
__global__ void k_wrepack(const float* __restrict__ w_mid,
                          __hip_bfloat16* __restrict__ wB2) {
    int idx = blockIdx.x * 256 + threadIdx.x;
    if (idx >= WB2_ELEMS) return;
    int kk  = idx & 31;
    int nl  = (idx >> 5) & 127;
    int q   = idx >> 12;             // (p*8+nt)*36 + kt
    int kt  = q % 36;
    int pnt = q / 36;
    int nt  = pnt & 7, p = pnt >> 3;
    int c = ((nt*8 + (nl >> 4)) << 1) + p;
    int m = nl & 15;
    int k = kt*32 + kk;
    int tap = k >> 7, ci = k & 127;
    wB2[idx] = __float2bfloat16(w_mid[((size_t)((c*16 + m)*128 + ci))*9 + tap]);
}

// ---------------------------------------------------------------------------
// Persistent-A implicit-GEMM conv, barrier-free K-loop, pipelined with
// sched_barrier(0) pinning: each step's {B-prefetch(u+2), A-ds_read(u+1),
// addr VALU} are pinned in issue order ABOVE the step's 16 MFMAs, so load
// latency lands under matrix execution. (R16/17/18 all compiled to
// VGPR=88 — the scheduler was sinking prefetches next to uses and erasing
// every source-level pipeline; this directive stops that.)
__global__ __launch_bounds__(256, 2) void k_conv(
    const __hip_bfloat16* __restrict__ xTp,
    const __hip_bfloat16* __restrict__ wB2,
    const float* __restrict__ w_pt,
    const float* __restrict__ b_pt,
    float* __restrict__ y) {
    __shared__ __hip_bfloat16 Atile[4*240*32];   // 61,440 B; plane kc: ci kc*32..+32

    const int combo = blockIdx.x & 7;      // XCD
    const int p   = combo & 1;
    const int ntp = combo >> 1;            // nt-pair 0..3
    const int i_  = blockIdx.x >> 3;       // 0..511
    const int nt  = ntp*2 + (i_ >> 8);     // consecutive blocks share nt (L1 reuse)
    const int mt  = i_ & 255;              // 0..255
    const int dil = 1 + p;
    const int b  = mt >> 5;                // image
    const int hb = (mt >> 2) & 7;          // row-block: output rows hb*8..+8
    const int wb = mt & 3;                 // col-block: output cols wb*16..+16
    const int H0 = hb*8, W0 = wb*16;       // halo origin (padded coords)

    const int t = threadIdx.x, lane = t & 63, wave = t >> 6;
    const int wm = wave >> 1, wn = wave & 1;
    const int lm = lane & 15, lg = lane >> 4;

    // ---- stage halo once: 4 planes x 240 px x 4 slots = 3840 units, 15 passes
    // phys slot = ls ^ ((px>>1)&3)   (R6 mechanism, R10/R17 zero-conflict shape)
    {
        const size_t gbase = ((size_t)(b*68 + H0))*68 + W0;
#pragma unroll
        for (int pass = 0; pass < 15; ++pass) {
            int si  = pass*256 + t;          // 0..3839
            int kc  = si / 960;
            int rem = si - kc*960;
            int px  = rem >> 2;
            int ls  = rem & 3;
            int prow = px / 20, pcol = px - prow*20;
            short8 v = *(const short8*)(xTp + (gbase + prow*68 + pcol)*128
                                        + kc*32 + ls*8);
            int phys = ls ^ ((px >> 1) & 3);
            *(short8*)(Atile + (kc*960 + px*4 + phys)*8) = v;
        }
    }

    // B pointer (R7/R17-proven): frag j at step u = +u*4096 + j*512
    const __hip_bfloat16* bptr = wB2 + (size_t)p*(8*36*4096) + (size_t)nt*(36*4096)
                               + (wn*64 + lm)*32 + lg*8;

    f32x4 acc[4][4];
#pragma unroll
    for (int i = 0; i < 4; ++i)
#pragma unroll
        for (int j = 0; j < 4; ++j) acc[i][j] = (f32x4){0.f, 0.f, 0.f, 0.f};

    // B prologue: steps 0,1 into breg[0],breg[1]
    short8 breg[3][4];
#pragma unroll
    for (int j = 0; j < 4; ++j) breg[0][j] = *(const short8*)(bptr + j*512);
#pragma unroll
    for (int j = 0; j < 4; ++j) breg[1][j] = *(const short8*)(bptr + 4096 + j*512);

    __syncthreads();   // staging visible; the ONLY block-wide barrier

    // A fragment read into a named dbuf slot (compile-time tap)
#define LOADA(dst, khc, kwc, kcc) do {                                        \
    int pc_ = 2 + dil*(kwc) + lm;                                             \
    int pr_ = (wm*4 + 2 + dil*(khc))*20 + pc_;                                \
    _Pragma("unroll")                                                         \
    for (int i_a = 0; i_a < 4; ++i_a) {                                       \
        int px_ = pr_ + 20*i_a;                                               \
        dst[i_a] = *(const short8*)(Atile + (kcc)*7680 + px_*32               \
                                    + ((lg ^ ((px_ >> 1) & 3)) << 3));        \
    }                                                                         \
  } while (0)

    short8 af[2][4];
    LOADA(af[0], -1, -1, 0);   // fragments for step u=0 (tap 0, kc 0)

#pragma unroll
    for (int u = 0; u < 36; ++u) {
        // B prefetch for step u+2 (distance-2, static %3 rotation)
        if (u + 2 < 36) {
#pragma unroll
            for (int j = 0; j < 4; ++j)
                breg[(u+2)%3][j] = *(const short8*)(bptr + (size_t)(u+2)*4096 + j*512);
        }
        // A fragment prefetch for step u+1
        if (u + 1 < 36) {
            const int un = u + 1, tapn = un >> 2, kcn = un & 3;
            const int khn = tapn/3 - 1, kwn = tapn%3 - 1;
            LOADA(af[(u+1)&1], khn, kwn, kcn);
        }
        // pin: all prefetch issue (loads + addr VALU) BEFORE this step's MFMAs
        __builtin_amdgcn_sched_barrier(0);
#pragma unroll
        for (int i = 0; i < 4; ++i)
#pragma unroll
            for (int j = 0; j < 4; ++j)
                acc[i][j] = __builtin_amdgcn_mfma_f32_16x16x32_bf16(
                    af[u&1][i], breg[u%3][j], acc[i][j], 0, 0, 0);
    }
#undef LOADA

    // epilogue: leaky -> *w_pt -> reduce over m (16 lanes) -> +b_pt -> y
#pragma unroll
    for (int j = 0; j < 4; ++j) {
        int n_g = nt*128 + wn*64 + j*16 + lm;
        int c = ((n_g >> 4) << 1) + p;     // uniform across the 16-lane group
        float wp = w_pt[c*16 + lm];        // m == lm
        float bp = b_pt[c];
#pragma unroll
        for (int i = 0; i < 4; ++i) {
            int h = H0 + wm*4 + i;
#pragma unroll
            for (int r = 0; r < 4; ++r) {
                float v = acc[i][j][r];
                v = v >= 0.f ? v : 0.1f*v;
                v *= wp;
                v += __shfl_xor(v, 1);
                v += __shfl_xor(v, 2);
                v += __shfl_xor(v, 4);
                v += __shfl_xor(v, 8);
                if (lm == 0) {
                    int w = W0 + lg*4 + r;
                    y[(size_t)(b*128 + c)*4096 + h*64 + w] = v + bp;
                }
            }
        }
    }
}

// ---------------------------------------------------------------------------
// per-(b,c)-plane partial sums (float4 loads, no atomics, deterministic)
__global__ __launch_bounds__(256) void k_ystat(const float* __restrict__ y,
                                               float2* __restrict__ partials) {
    int P = blockIdx.x;                 // plane = b*128 + c
    const float4* base = (const float4*)(y + (size_t)P*4096);
    int t = threadIdx.x;
    float s = 0.f, s2 = 0.f;
#pragma unroll
    for (int i = 0; i < 4; ++i) {
        float4 v = base[t + i*256];
        s  += v.x + v.y + v.z + v.w;
        s2 += v.x*v.x + v.y*v.y + v.z*v.z + v.w*v.w;
    }
#pragma unroll
    for (int o = 32; o; o >>= 1) { s += __shfl_down(s, o); s2 += __shfl_down(s2, o); }
    __shared__ float ss[4], ss2[4];
    if ((t & 63) == 0) { ss[t >> 6] = s; ss2[t >> 6] = s2; }
    __syncthreads();
    if (t == 0)
        partials[P] = make_float2(ss[0]+ss[1]+ss[2]+ss[3], ss2[0]+ss2[1]+ss2[2]+ss2[3]);
}

// BN finalize + apply + ReLU. Block covers 256 float4 = quarter of one plane.
__global__ __launch_bounds__(256) void k_bn_apply(float* __restrict__ y,
                                                  const float2* __restrict__ partials,
                                                  const float* __restrict__ gamma,
                                                  const float* __restrict__ beta) {
    int bid = blockIdx.x;
    int c = (bid >> 2) & 127;
    float s = 0.f, s2 = 0.f;
#pragma unroll
    for (int b = 0; b < 8; ++b) {
        float2 pr = partials[b*128 + c];
        s += pr.x; s2 += pr.y;
    }
    float mean = s * (1.f/32768.f);
    float var  = s2 * (1.f/32768.f) - mean*mean;
    float scale = gamma[c] * rsqrtf(var + EPSV);
    float shift = beta[c] - mean*scale;
    float4* y4 = (float4*)y;
    int idx = bid*256 + threadIdx.x;
    float4 v = y4[idx];
    v.x = fmaxf(v.x*scale + shift, 0.f);
    v.y = fmaxf(v.y*scale + shift, 0.f);
    v.z = fmaxf(v.z*scale + shift, 0.f);
    v.w = fmaxf(v.w*scale + shift, 0.f);
    y4[idx] = v;
}

// ---------------------------------------------------------------------------
extern "C" void kernel_launch(void* const* d_in, const int* in_sizes, int n_in,
                              void* d_out, int out_size, void* d_ws, size_t ws_size,
                              hipStream_t stream) {
    const float* x     = (const float*)d_in[0];
    const float* w_mid = (const float*)d_in[1];
    const float* w_pt  = (const float*)d_in[2];
    const float* b_pt  = (const float*)d_in[3];
    const float* gamma = (const float*)d_in[4];
    const float* beta  = (const float*)d_in[5];
    float* y = (float*)d_out;

    __hip_bfloat16* wB2 = (__hip_bfloat16*)d_ws;
    __hip_bfloat16* xTp = (__hip_bfloat16*)((char*)d_ws + WB2_BYTES);
    float2* partials    = (float2*)((char*)d_ws + STATS_OFF);

    hipMemsetAsync(xTp, 0, XTP_BYTES, stream);                  // zero halo
    k_xpad<<<512, 256, 0, stream>>>(x, xTp);
    k_wrepack<<<(WB2_ELEMS + 255) / 256, 256, 0, stream>>>(w_mid, wB2);
    k_conv<<<4096, 256, 0, stream>>>(xTp, wB2, w_pt, b_pt, y);
    k_ystat<<<1024, 256, 0, stream>>>(y, partials);
    k_bn_apply<<<4096, 256, 0, stream>>>(y, partials, gamma, beta);
}